// Round 16
// baseline (289.665 us; speedup 1.0000x reference)
//
#include <hip/hip_runtime.h>

#define NN 50000
#define NE 800000
#define ET 850000   // NE + NN self-loops
#define NG 64
#define D  128
#define NB 196      // CSR buckets of 256 dst nodes
#define CAP 5120    // temp capacity per bucket (avg 4082, huge slack)
#define CHUNK 4096  // edges per k_bucket block (196 blocks -> full CU coverage)

typedef unsigned short u16;
typedef unsigned int   u32;
typedef short bf16x8 __attribute__((ext_vector_type(8)));
typedef float f32x4  __attribute__((ext_vector_type(4)));

__device__ __forceinline__ u16 f2b(float f){
  u32 u = __float_as_uint(f);
  u32 r = (u + 0x7fffu + ((u >> 16) & 1u)) >> 16;
  return (u16)r;
}
__device__ __forceinline__ u32 pack2(float a, float b){
  return (u32)f2b(a) | ((u32)f2b(b) << 16);
}
__device__ __forceinline__ float lo16f(u32 u){ return __uint_as_float(u << 16); }
__device__ __forceinline__ float hi16f(u32 u){ return __uint_as_float(u & 0xffff0000u); }

// ---------------- CSR stage 1: bucket edges by dst>>8 (block-local counting sort) ----
__global__ __launch_bounds__(256) void k_bucket(const int* __restrict__ srcE, const int* __restrict__ dstE,
                                                int* __restrict__ gCur, int* __restrict__ temp){
  __shared__ int hist[256], hbase[256], hpos[256], gbase[256];
  __shared__ int sorted[CHUNK];
  int tid = threadIdx.x;
  int e0 = blockIdx.x * CHUNK;
  int e1 = e0 + CHUNK; if (e1 > NE) e1 = NE;
  int cnt = e1 - e0;
  hist[tid] = 0;
  __syncthreads();
  for (int i = e0 + tid; i < e1; i += 256)
    atomicAdd(&hist[(u32)dstE[i] >> 8], 1);
  __syncthreads();
  int v = hist[tid];
  hbase[tid] = v;
  __syncthreads();
  for (int off = 1; off < 256; off <<= 1){
    int t = (tid >= off) ? hbase[tid-off] : 0;
    __syncthreads();
    hbase[tid] += t;
    __syncthreads();
  }
  int excl = hbase[tid] - v;     // exclusive prefix within chunk
  __syncthreads();
  hbase[tid] = excl;
  hpos[tid]  = excl;
  __syncthreads();
  for (int i = e0 + tid; i < e1; i += 256){
    int d = dstE[i], sr = srcE[i];
    int idx = atomicAdd(&hpos[(u32)d >> 8], 1);
    sorted[idx] = (d << 16) | sr;
  }
  __syncthreads();
  if (tid < NB && hist[tid] > 0)
    gbase[tid] = atomicAdd(&gCur[tid], hist[tid]);
  __syncthreads();
  for (int i = tid; i < cnt; i += 256){
    int vv = sorted[i];
    int b = (u32)vv >> 24;
    int pos = gbase[b] + (i - hbase[b]);
    if (pos < CAP) temp[b*CAP + pos] = vv;
  }
}

// ---------------- CSR stage 2: per-bucket place (offs + srcs); bucket starts inline ----
__global__ __launch_bounds__(256) void k_place(const int* __restrict__ temp, const int* __restrict__ gCur,
                                               int* __restrict__ offs, int* __restrict__ srcs){
  __shared__ int cnt256[256], pfx[256], pos[256], sb[256];
  int b = blockIdx.x, tid = threadIdx.x;
  // bucket starts: prefix over gCur[i] + nodes(i), recomputed per block
  int nodes_i = (tid < NB) ? ((tid == NB-1) ? (NN - (NB-1)*256) : 256) : 0;
  int bv = (tid < NB) ? gCur[tid] + nodes_i : 0;
  sb[tid] = bv;
  __syncthreads();
  for (int off = 1; off < 256; off <<= 1){
    int t = (tid >= off) ? sb[tid-off] : 0;
    __syncthreads();
    sb[tid] += t;
    __syncthreads();
  }
  int base = (b == 0) ? 0 : sb[b-1];
  if (b == 0 && tid == 0) offs[NN] = ET;
  int n0 = b << 8;
  int nNodes = NN - n0; if (nNodes > 256) nNodes = 256;
  int count = gCur[b];
  const int* tb = temp + b*CAP;
  cnt256[tid] = 0;
  __syncthreads();
  for (int i = tid; i < count; i += 256)
    atomicAdd(&cnt256[((u32)tb[i] >> 16) & 255], 1);
  __syncthreads();
  int own = cnt256[tid] + (tid < nNodes ? 1 : 0);   // +1 self-loop slot
  pfx[tid] = own;
  __syncthreads();
  for (int off = 1; off < 256; off <<= 1){
    int t = (tid >= off) ? pfx[tid-off] : 0;
    __syncthreads();
    pfx[tid] += t;
    __syncthreads();
  }
  int excl = pfx[tid] - own;
  __syncthreads();
  pos[tid] = excl + 1;                // edge cursor (slot 0 = self-loop)
  __syncthreads();
  if (tid < nNodes){
    offs[n0 + tid] = base + excl;
    srcs[base + excl] = n0 + tid;     // self-loop first
  }
  for (int i = tid; i < count; i += 256){
    int vv = tb[i];
    int d = ((u32)vv >> 16) & 255;
    int k = atomicAdd(&pos[d], 1);
    srcs[base + k] = vv & 0xFFFF;
  }
}

// ---------------- MFMA GEMM + fused att dots ----------------------------------
// FUSE_BN=0: plain f32 X; also zeroes the scratch block (bsum/bsq/pooled/gCur/pcnt).
// FUSE_BN=1: f32 X + in-kernel BN-finalize + BN+ELU.
// BM=128, 512 threads (8 waves). Wave w owns cols w*16..+15; 8 row-chunks of 16.
// W staged in-kernel: f32 [k][c] -> bf16 [c][k] (W is L2-resident across blocks).
// C/D frag layout (verified): col = lane&15, row = (lane>>4)*4 + reg.
template<int FUSE_BN>
__global__ __launch_bounds__(512) void k_gemm(const float* __restrict__ X, const float* __restrict__ W,
                                              u16* __restrict__ Ybf,
                                              const float* __restrict__ att_s, const float* __restrict__ att_d,
                                              float* __restrict__ asrc, float* __restrict__ adst,
                                              const float* __restrict__ bsum, const float* __restrict__ bsq,
                                              const float* __restrict__ gamma, const float* __restrict__ beta,
                                              u32* __restrict__ zbase, int zwords,
                                              int nrows){
  __shared__ u16 Xs[128*136];    // 34.8 KB (reused as sDot after barrier)
  __shared__ u16 WT[128*136];    // 34.8 KB
  __shared__ float sBsc[128], sBsh[128];
  int tid = threadIdx.x;
  int row0 = blockIdx.x * 128;
  if (FUSE_BN == 0){
    int gi = blockIdx.x*512 + tid;
    if (gi < zwords) zbase[gi] = 0u;
  }
  if (FUSE_BN){
    if (tid < 128){
      float mu  = bsum[tid] * (1.f/NN);
      float var = bsq[tid] * (1.f/NN) - mu*mu;
      float sc  = gamma[tid] * rsqrtf(var + 1e-5f);
      sBsc[tid] = sc;
      sBsh[tid] = beta[tid] - mu*sc;
    }
    __syncthreads();
  }
  // ---- stage X (f32 -> bf16), optional BN+ELU: 4096 float4, 8 per thread ----
  #pragma unroll
  for (int t = 0; t < 8; t++){
    int i = tid + t*512;
    int r = i >> 5, k4 = i & 31;
    int gr = row0 + r;
    float4 v = (gr < nrows) ? ((const float4*)(X + (size_t)gr*D))[k4]
                            : make_float4(0.f,0.f,0.f,0.f);
    if (FUSE_BN){
      float4 sc = ((const float4*)sBsc)[k4];
      float4 sh = ((const float4*)sBsh)[k4];
      v.x = fmaf(v.x, sc.x, sh.x); v.y = fmaf(v.y, sc.y, sh.y);
      v.z = fmaf(v.z, sc.z, sh.z); v.w = fmaf(v.w, sc.w, sh.w);
      v.x = v.x > 0.f ? v.x : expm1f(v.x);
      v.y = v.y > 0.f ? v.y : expm1f(v.y);
      v.z = v.z > 0.f ? v.z : expm1f(v.z);
      v.w = v.w > 0.f ? v.w : expm1f(v.w);
    }
    *(uint2*)&Xs[r*136 + k4*4] = make_uint2(pack2(v.x, v.y), pack2(v.z, v.w));
  }
  // ---- stage W transposed (f32 [k][c] -> bf16 [c][k]) ----
  {
    int c = tid & 127, kp = tid >> 7;      // kp 0..3
    #pragma unroll
    for (int t = 0; t < 16; t++){
      int kk = kp + t*4;                   // k-pair index 0..63
      float w0 = W[(size_t)(2*kk)*D + c];
      float w1 = W[(size_t)(2*kk+1)*D + c];
      *(u32*)&WT[c*136 + 2*kk] = pack2(w0, w1);
    }
  }
  __syncthreads();
  int w = tid >> 6, l = tid & 63;
  int l15 = l & 15, lq = l >> 4;
  int cw = w*16;
  bf16x8 bfr[4];
  #pragma unroll
  for (int ks = 0; ks < 4; ks++)
    bfr[ks] = *(const bf16x8*)&WT[(cw + l15)*136 + ks*32 + lq*8];
  f32x4 acc[8];
  #pragma unroll
  for (int m = 0; m < 8; m++) acc[m] = (f32x4){0.f,0.f,0.f,0.f};
  #pragma unroll
  for (int m = 0; m < 8; m++){
    #pragma unroll
    for (int ks = 0; ks < 4; ks++){
      bf16x8 af = *(const bf16x8*)&Xs[(m*16 + l15)*136 + ks*32 + lq*8];
      acc[m] = __builtin_amdgcn_mfma_f32_16x16x32_bf16(af, bfr[ks], acc[m], 0, 0, 0);
    }
  }
  __syncthreads();                          // Xs reads done; alias sDot onto Xs
  float* sDotS = (float*)Xs;                // [8 waves][128 rows]
  float* sDotD = sDotS + 1024;
  // ---- fused attention dots ----
  {
    float as_c = att_s[cw + l15];
    float ad_c = att_d[cw + l15];
    #pragma unroll
    for (int m = 0; m < 8; m++){
      #pragma unroll
      for (int i = 0; i < 4; i++){
        float ps = acc[m][i] * as_c;
        float pd = acc[m][i] * ad_c;
        #pragma unroll
        for (int msk = 1; msk <= 8; msk <<= 1){
          ps += __shfl_xor(ps, msk);
          pd += __shfl_xor(pd, msk);
        }
        if (l15 == 0){
          int r = m*16 + lq*4 + i;
          sDotS[w*128 + r] = ps;
          sDotD[w*128 + r] = pd;
        }
      }
    }
  }
  // ---- C store (row-major): pack bf16 pairs via shfl ----
  #pragma unroll
  for (int m = 0; m < 8; m++){
    #pragma unroll
    for (int i = 0; i < 4; i++){
      float v = acc[m][i];
      float nb = __shfl_xor(v, 1);
      if (!(l & 1)){
        int gr = row0 + m*16 + lq*4 + i;
        if (gr < nrows)
          *(u32*)&Ybf[(size_t)gr*D + cw + l15] = pack2(v, nb);
      }
    }
  }
  __syncthreads();
  {
    int r = tid >> 2, h = tid & 3;          // 512 threads: 128 rows x 4 heads
    int gr = row0 + r;
    if (gr < nrows){
      asrc[gr*4 + h] = sDotS[(2*h)*128 + r] + sDotS[(2*h+1)*128 + r];
      adst[gr*4 + h] = sDotD[(2*h)*128 + r] + sDotD[(2*h+1)*128 + r];
    }
  }
}

// ---------------- GAT edge softmax + aggregate: single pass, no max shift ------
__global__ __launch_bounds__(256) void k_edge(
                       const u16* __restrict__ hb, const float* __restrict__ asrc,
                       const float* __restrict__ adst, const int* __restrict__ offs,
                       const int* __restrict__ srcs, const float* __restrict__ bias,
                       float* __restrict__ out){
  __shared__ uint2 sPk[4][4][17];   // {byte offset src*256, alpha bits}
  int w = threadIdx.x >> 6;
  int lane = threadIdx.x & 63;
  int n = blockIdx.x*4 + w;
  int off0 = offs[n];
  int deg  = offs[n+1] - off0;
  int hd = lane >> 4, j16 = lane & 15;
  float adh = adst[n*4 + hd];
  int half = lane >> 5, q = lane & 31;
  int hg = q >> 3;
  int qb = q*8;
  float denp = 0.f;
  float acc0=0.f, acc1=0.f, acc2=0.f, acc3=0.f;
  const char* hbase = (const char*)hb;
  const int* sp = srcs + off0;
  // preload chunk 0 alpha inputs
  int sj = (j16 < deg) ? sp[j16] : 0;
  float av = asrc[sj*4 + hd];
  for (int base = 0; base < deg; base += 16){
    int lim = deg - base; if (lim > 16) lim = 16;
    // ---- prefetch next chunk's srcs ----
    int nbase = base + 16;
    bool hasn = (nbase < deg);
    int sjn = 0;
    if (hasn){
      int idx = nbase + j16;
      sjn = (idx < deg) ? sp[idx] : 0;
    }
    // ---- alpha for current chunk ----
    float al;
    if (j16 < lim){
      float e = av + adh;
      e = e > 0.f ? e : 0.2f*e;
      al = __expf(e);
    } else al = 0.f;
    denp += al;
    sPk[w][hd][j16] = make_uint2((u32)sj << 8, __float_as_uint(al));
    // ---- prefetch next chunk's asrc (depends on sjn) ----
    float avn = hasn ? asrc[sjn*4 + hd] : 0.f;
    // ---- gather + accumulate ----
    if (lim == 16){
      uint2 p0 = sPk[w][hg][half],      p1 = sPk[w][hg][2+half];
      uint2 p2 = sPk[w][hg][4+half],    p3 = sPk[w][hg][6+half];
      uint2 p4 = sPk[w][hg][8+half],    p5 = sPk[w][hg][10+half];
      uint2 p6 = sPk[w][hg][12+half],   p7 = sPk[w][hg][14+half];
      uint2 v0 = *(const uint2*)(hbase + p0.x + qb);
      uint2 v1 = *(const uint2*)(hbase + p1.x + qb);
      uint2 v2 = *(const uint2*)(hbase + p2.x + qb);
      uint2 v3 = *(const uint2*)(hbase + p3.x + qb);
      uint2 v4 = *(const uint2*)(hbase + p4.x + qb);
      uint2 v5 = *(const uint2*)(hbase + p5.x + qb);
      uint2 v6 = *(const uint2*)(hbase + p6.x + qb);
      uint2 v7 = *(const uint2*)(hbase + p7.x + qb);
      float a0 = __uint_as_float(p0.y), a1 = __uint_as_float(p1.y);
      float a2 = __uint_as_float(p2.y), a3 = __uint_as_float(p3.y);
      float a4 = __uint_as_float(p4.y), a5 = __uint_as_float(p5.y);
      float a6 = __uint_as_float(p6.y), a7 = __uint_as_float(p7.y);
      acc0 = fmaf(a0, lo16f(v0.x), acc0); acc1 = fmaf(a0, hi16f(v0.x), acc1);
      acc2 = fmaf(a0, lo16f(v0.y), acc2); acc3 = fmaf(a0, hi16f(v0.y), acc3);
      acc0 = fmaf(a1, lo16f(v1.x), acc0); acc1 = fmaf(a1, hi16f(v1.x), acc1);
      acc2 = fmaf(a1, lo16f(v1.y), acc2); acc3 = fmaf(a1, hi16f(v1.y), acc3);
      acc0 = fmaf(a2, lo16f(v2.x), acc0); acc1 = fmaf(a2, hi16f(v2.x), acc1);
      acc2 = fmaf(a2, lo16f(v2.y), acc2); acc3 = fmaf(a2, hi16f(v2.y), acc3);
      acc0 = fmaf(a3, lo16f(v3.x), acc0); acc1 = fmaf(a3, hi16f(v3.x), acc1);
      acc2 = fmaf(a3, lo16f(v3.y), acc2); acc3 = fmaf(a3, hi16f(v3.y), acc3);
      acc0 = fmaf(a4, lo16f(v4.x), acc0); acc1 = fmaf(a4, hi16f(v4.x), acc1);
      acc2 = fmaf(a4, lo16f(v4.y), acc2); acc3 = fmaf(a4, hi16f(v4.y), acc3);
      acc0 = fmaf(a5, lo16f(v5.x), acc0); acc1 = fmaf(a5, hi16f(v5.x), acc1);
      acc2 = fmaf(a5, lo16f(v5.y), acc2); acc3 = fmaf(a5, hi16f(v5.y), acc3);
      acc0 = fmaf(a6, lo16f(v6.x), acc0); acc1 = fmaf(a6, hi16f(v6.x), acc1);
      acc2 = fmaf(a6, lo16f(v6.y), acc2); acc3 = fmaf(a6, hi16f(v6.y), acc3);
      acc0 = fmaf(a7, lo16f(v7.x), acc0); acc1 = fmaf(a7, hi16f(v7.x), acc1);
      acc2 = fmaf(a7, lo16f(v7.y), acc2); acc3 = fmaf(a7, hi16f(v7.y), acc3);
    } else {
      for (int j = 0; j < lim; j += 8){
        uint2 pA = sPk[w][hg][j+half],   pB = sPk[w][hg][j+2+half];
        uint2 pC = sPk[w][hg][j+4+half], pD = sPk[w][hg][j+6+half];
        uint2 vA = *(const uint2*)(hbase + pA.x + qb);
        uint2 vB = *(const uint2*)(hbase + pB.x + qb);
        uint2 vC = *(const uint2*)(hbase + pC.x + qb);
        uint2 vD = *(const uint2*)(hbase + pD.x + qb);
        float aA = __uint_as_float(pA.y), aB = __uint_as_float(pB.y);
        float aC = __uint_as_float(pC.y), aD = __uint_as_float(pD.y);
        acc0 = fmaf(aA, lo16f(vA.x), acc0); acc1 = fmaf(aA, hi16f(vA.x), acc1);
        acc2 = fmaf(aA, lo16f(vA.y), acc2); acc3 = fmaf(aA, hi16f(vA.y), acc3);
        acc0 = fmaf(aB, lo16f(vB.x), acc0); acc1 = fmaf(aB, hi16f(vB.x), acc1);
        acc2 = fmaf(aB, lo16f(vB.y), acc2); acc3 = fmaf(aB, hi16f(vB.y), acc3);
        acc0 = fmaf(aC, lo16f(vC.x), acc0); acc1 = fmaf(aC, hi16f(vC.x), acc1);
        acc2 = fmaf(aC, lo16f(vC.y), acc2); acc3 = fmaf(aC, hi16f(vC.y), acc3);
        acc0 = fmaf(aD, lo16f(vD.x), acc0); acc1 = fmaf(aD, hi16f(vD.x), acc1);
        acc2 = fmaf(aD, lo16f(vD.y), acc2); acc3 = fmaf(aD, hi16f(vD.y), acc3);
      }
    }
    sj = sjn; av = avn;
  }
  denp += __shfl_xor(denp, 1);
  denp += __shfl_xor(denp, 2);
  denp += __shfl_xor(denp, 4);
  denp += __shfl_xor(denp, 8);
  acc0 += __shfl_xor(acc0, 32);
  acc1 += __shfl_xor(acc1, 32);
  acc2 += __shfl_xor(acc2, 32);
  acc3 += __shfl_xor(acc3, 32);
  float inv = 1.f / __shfl(denp, hg*16);
  if (half == 0){
    int cb = q*4;
    float4 o;
    o.x = acc0*inv + bias[cb];
    o.y = acc1*inv + bias[cb+1];
    o.z = acc2*inv + bias[cb+2];
    o.w = acc3*inv + bias[cb+3];
    ((float4*)(out + (size_t)n*D))[q] = o;
  }
}

// ---------------- BatchNorm stats (f32 input) ----------------
__global__ __launch_bounds__(256) void k_bnstat(const float* __restrict__ B,
                                                float* __restrict__ bsum, float* __restrict__ bsq){
  __shared__ float sS[256], sQ[256];
  int tid = threadIdx.x;
  int c = tid & 127;
  int rr = tid >> 7;
  int r0 = blockIdx.x * 64;
  int r1 = r0 + 64; if (r1 > NN) r1 = NN;
  float s = 0.f, qv = 0.f;
  for (int r = r0 + rr; r < r1; r += 2){
    float v = B[(size_t)r*D + c];
    s += v; qv += v*v;
  }
  sS[tid] = s; sQ[tid] = qv;
  __syncthreads();
  if (tid < 128){
    atomicAdd(&bsum[c], sS[tid] + sS[tid+128]);
    atomicAdd(&bsq[c],  sQ[tid] + sQ[tid+128]);
  }
}

// ---------------- global mean pool (batch sorted): accumulate + last-block finalize ----
#define POOL_ROWS 50
__global__ __launch_bounds__(256) void k_pool(const float* __restrict__ h2, const int* __restrict__ batch,
                                              float* __restrict__ pooled, int* __restrict__ pcnt,
                                              float* __restrict__ out){
  int c = threadIdx.x & 127;
  int hsel = threadIdx.x >> 7;
  int r0 = blockIdx.x * POOL_ROWS;
  int r1 = r0 + POOL_ROWS; if (r1 > NN) r1 = NN;
  float s = 0.f; int g = -1;
  for (int r = r0 + hsel; r < r1; r += 2){
    int bg = batch[r];
    if (bg != g){
      if (g >= 0) atomicAdd(&pooled[g*D + c], s);
      g = bg; s = 0.f;
    }
    s += h2[(size_t)r*D + c];
  }
  if (g >= 0) atomicAdd(&pooled[g*D + c], s);
  // last-block finalize (divide by counts)
  __shared__ int lastFlag;
  __shared__ float scnt[NG];
  __threadfence();
  __syncthreads();
  if (threadIdx.x == 0){
    int v = atomicAdd(pcnt, 1);
    lastFlag = (v == (int)gridDim.x - 1) ? 1 : 0;
  }
  __syncthreads();
  if (lastFlag){
    if (threadIdx.x < NG){
      int gg = threadIdx.x;
      int lo = 0, hi = NN;
      while (lo < hi){ int mid = (lo+hi) >> 1; if (batch[mid] < gg) lo = mid+1; else hi = mid; }
      int a = lo, b = NN;
      while (a < b){ int mid = (a+b) >> 1; if (batch[mid] < gg+1) a = mid+1; else b = mid; }
      int cn = a - lo;
      scnt[gg] = (float)(cn > 1 ? cn : 1);
    }
    __syncthreads();
    for (int i = threadIdx.x; i < NG*D; i += 256){
      float tot = atomicAdd(&pooled[i], 0.f);    // coherent read across XCD L2s
      out[i] = tot / scnt[i >> 7];
    }
  }
}

extern "C" void kernel_launch(void* const* d_in, const int* in_sizes, int n_in,
                              void* d_out, int out_size, void* d_ws, size_t ws_size,
                              hipStream_t stream){
  (void)in_sizes; (void)n_in; (void)out_size; (void)ws_size;
  const float* x   = (const float*)d_in[0];
  const int* ei    = (const int*)d_in[1];
  const int* batch = (const int*)d_in[2];
  const float* W1  = (const float*)d_in[3];
  const float* as1 = (const float*)d_in[4];
  const float* ad1 = (const float*)d_in[5];
  const float* b1  = (const float*)d_in[6];
  const float* g1  = (const float*)d_in[7];
  const float* be1 = (const float*)d_in[8];
  const float* W2  = (const float*)d_in[9];
  const float* as2 = (const float*)d_in[10];
  const float* ad2 = (const float*)d_in[11];
  const float* b2  = (const float*)d_in[12];
  float* outp = (float*)d_out;

  float* B    = (float*)d_ws;            // 6.4M f32
  float* asr  = B + 6400000;             // 200K
  float* ads  = asr + 200000;            // 200K
  // ---- contiguous zero-block (zeroed by k_gemm<0> prologue) ----
  float* bsum = ads + 200000;            // 128
  float* bsq  = bsum + 128;              // 128
  float* pooled = bsq + 128;             // 8192
  int* gCur   = (int*)(pooled + NG*D);   // 256
  int* pcnt   = gCur + 256;              // 1 (+3 pad)
  // ---- end zero-block (8708 words) ----
  int* offs   = pcnt + 4;                // 50001
  int* srcs   = offs + (NN+1);           // 850000
  int* temp   = srcs + ET;               // 196*5120 = 1003520
  u16* hb     = (u16*)(temp + NB*CAP);   // 6.4M bf16 (12.8 MB)
  u32* zbase  = (u32*)bsum;
  const int ZWORDS = 128 + 128 + NG*D + 256 + 4;   // 8708

  const int* srcE = ei;
  const int* dstE = ei + NE;

  // layer-1 GEMM (+att dots, + scratch zeroing)
  k_gemm<0><<<391, 512, 0, stream>>>(x, W1, hb, as1, ad1, asr, ads,
                                     nullptr, nullptr, nullptr, nullptr,
                                     zbase, ZWORDS, NN);
  // CSR build: bucket -> place (bucket starts inline)
  k_bucket<<<(NE + CHUNK - 1)/CHUNK, 256, 0, stream>>>(srcE, dstE, gCur, temp);
  k_place<<<NB, 256, 0, stream>>>(temp, gCur, offs, srcs);
  k_edge<<<NN/4, 256, 0, stream>>>(hb, asr, ads, offs, srcs, b1, B);
  k_bnstat<<<782, 256, 0, stream>>>(B, bsum, bsq);
  // layer-2 GEMM: fused BN-finalize + BN+ELU on input (+att dots)
  k_gemm<1><<<391, 512, 0, stream>>>(B, W2, hb, as2, ad2, asr, ads,
                                     bsum, bsq, g1, be1, nullptr, 0, NN);
  k_edge<<<NN/4, 256, 0, stream>>>(hb, asr, ads, offs, srcs, b2, outp);
  // pool: accumulate + last-block divide
  k_pool<<<(NN + POOL_ROWS - 1)/POOL_ROWS, 256, 0, stream>>>(outp, batch, pooled, pcnt, outp + 6400000);
}

// Round 17
// 218.955 us; speedup vs baseline: 1.3229x; 1.3229x over previous
//
#include <hip/hip_runtime.h>

#define NN 50000
#define NE 800000
#define ET 850000   // NE + NN self-loops
#define NG 64
#define D  128
#define NB 196      // CSR buckets of 256 dst nodes
#define CAP 5120    // temp capacity per bucket (avg 4082, huge slack)
#define CHUNK 4096  // edges per k_bucket block (196 blocks -> full CU coverage)

typedef unsigned short u16;
typedef unsigned int   u32;
typedef short bf16x8 __attribute__((ext_vector_type(8)));
typedef float f32x4  __attribute__((ext_vector_type(4)));

__device__ __forceinline__ u16 f2b(float f){
  u32 u = __float_as_uint(f);
  u32 r = (u + 0x7fffu + ((u >> 16) & 1u)) >> 16;
  return (u16)r;
}
__device__ __forceinline__ u32 pack2(float a, float b){
  return (u32)f2b(a) | ((u32)f2b(b) << 16);
}
__device__ __forceinline__ float lo16f(u32 u){ return __uint_as_float(u << 16); }
__device__ __forceinline__ float hi16f(u32 u){ return __uint_as_float(u & 0xffff0000u); }

// ---------------- CSR stage 1: bucket edges by dst>>8 (block-local counting sort) ----
__global__ __launch_bounds__(256) void k_bucket(const int* __restrict__ srcE, const int* __restrict__ dstE,
                                                int* __restrict__ gCur, int* __restrict__ temp){
  __shared__ int hist[256], hbase[256], hpos[256], gbase[256];
  __shared__ int sorted[CHUNK];
  int tid = threadIdx.x;
  int e0 = blockIdx.x * CHUNK;
  int e1 = e0 + CHUNK; if (e1 > NE) e1 = NE;
  int cnt = e1 - e0;
  hist[tid] = 0;
  __syncthreads();
  for (int i = e0 + tid; i < e1; i += 256)
    atomicAdd(&hist[(u32)dstE[i] >> 8], 1);
  __syncthreads();
  int v = hist[tid];
  hbase[tid] = v;
  __syncthreads();
  for (int off = 1; off < 256; off <<= 1){
    int t = (tid >= off) ? hbase[tid-off] : 0;
    __syncthreads();
    hbase[tid] += t;
    __syncthreads();
  }
  int excl = hbase[tid] - v;     // exclusive prefix within chunk
  __syncthreads();
  hbase[tid] = excl;
  hpos[tid]  = excl;
  __syncthreads();
  for (int i = e0 + tid; i < e1; i += 256){
    int d = dstE[i], sr = srcE[i];
    int idx = atomicAdd(&hpos[(u32)d >> 8], 1);
    sorted[idx] = (d << 16) | sr;
  }
  __syncthreads();
  if (tid < NB && hist[tid] > 0)
    gbase[tid] = atomicAdd(&gCur[tid], hist[tid]);
  __syncthreads();
  for (int i = tid; i < cnt; i += 256){
    int vv = sorted[i];
    int b = (u32)vv >> 24;
    int pos = gbase[b] + (i - hbase[b]);
    if (pos < CAP) temp[b*CAP + pos] = vv;
  }
}

// ---------------- CSR stage 2: per-bucket place (offs + srcs); bucket starts inline ----
__global__ __launch_bounds__(256) void k_place(const int* __restrict__ temp, const int* __restrict__ gCur,
                                               int* __restrict__ offs, int* __restrict__ srcs){
  __shared__ int cnt256[256], pfx[256], pos[256], sb[256];
  int b = blockIdx.x, tid = threadIdx.x;
  // bucket starts: prefix over gCur[i] + nodes(i), recomputed per block
  int nodes_i = (tid < NB) ? ((tid == NB-1) ? (NN - (NB-1)*256) : 256) : 0;
  int bv = (tid < NB) ? gCur[tid] + nodes_i : 0;
  sb[tid] = bv;
  __syncthreads();
  for (int off = 1; off < 256; off <<= 1){
    int t = (tid >= off) ? sb[tid-off] : 0;
    __syncthreads();
    sb[tid] += t;
    __syncthreads();
  }
  int base = (b == 0) ? 0 : sb[b-1];
  if (b == 0 && tid == 0) offs[NN] = ET;
  int n0 = b << 8;
  int nNodes = NN - n0; if (nNodes > 256) nNodes = 256;
  int count = gCur[b];
  const int* tb = temp + b*CAP;
  cnt256[tid] = 0;
  __syncthreads();
  for (int i = tid; i < count; i += 256)
    atomicAdd(&cnt256[((u32)tb[i] >> 16) & 255], 1);
  __syncthreads();
  int own = cnt256[tid] + (tid < nNodes ? 1 : 0);   // +1 self-loop slot
  pfx[tid] = own;
  __syncthreads();
  for (int off = 1; off < 256; off <<= 1){
    int t = (tid >= off) ? pfx[tid-off] : 0;
    __syncthreads();
    pfx[tid] += t;
    __syncthreads();
  }
  int excl = pfx[tid] - own;
  __syncthreads();
  pos[tid] = excl + 1;                // edge cursor (slot 0 = self-loop)
  __syncthreads();
  if (tid < nNodes){
    offs[n0 + tid] = base + excl;
    srcs[base + excl] = n0 + tid;     // self-loop first
  }
  for (int i = tid; i < count; i += 256){
    int vv = tb[i];
    int d = ((u32)vv >> 16) & 255;
    int k = atomicAdd(&pos[d], 1);
    srcs[base + k] = vv & 0xFFFF;
  }
}

// ---------------- MFMA GEMM + fused att dots ----------------------------------
// FUSE_BN=0: plain f32 X; also zeroes the scratch block (bsum/bsq/pooled/gCur).
// FUSE_BN=1: f32 X + in-kernel BN-finalize + BN+ELU.
// BM=128, 512 threads (8 waves). Wave w owns cols w*16..+15; 8 row-chunks of 16.
// W staged in-kernel: f32 [k][c] -> bf16 [c][k] (W is L2-resident across blocks).
// C/D frag layout (verified): col = lane&15, row = (lane>>4)*4 + reg.
template<int FUSE_BN>
__global__ __launch_bounds__(512) void k_gemm(const float* __restrict__ X, const float* __restrict__ W,
                                              u16* __restrict__ Ybf,
                                              const float* __restrict__ att_s, const float* __restrict__ att_d,
                                              float* __restrict__ asrc, float* __restrict__ adst,
                                              const float* __restrict__ bsum, const float* __restrict__ bsq,
                                              const float* __restrict__ gamma, const float* __restrict__ beta,
                                              u32* __restrict__ zbase, int zwords,
                                              int nrows){
  __shared__ u16 Xs[128*136];    // 34.8 KB (reused as sDot after barrier)
  __shared__ u16 WT[128*136];    // 34.8 KB
  __shared__ float sBsc[128], sBsh[128];
  int tid = threadIdx.x;
  int row0 = blockIdx.x * 128;
  if (FUSE_BN == 0){
    int gi = blockIdx.x*512 + tid;
    if (gi < zwords) zbase[gi] = 0u;
  }
  if (FUSE_BN){
    if (tid < 128){
      float mu  = bsum[tid] * (1.f/NN);
      float var = bsq[tid] * (1.f/NN) - mu*mu;
      float sc  = gamma[tid] * rsqrtf(var + 1e-5f);
      sBsc[tid] = sc;
      sBsh[tid] = beta[tid] - mu*sc;
    }
    __syncthreads();
  }
  // ---- stage X (f32 -> bf16), optional BN+ELU: 4096 float4, 8 per thread ----
  #pragma unroll
  for (int t = 0; t < 8; t++){
    int i = tid + t*512;
    int r = i >> 5, k4 = i & 31;
    int gr = row0 + r;
    float4 v = (gr < nrows) ? ((const float4*)(X + (size_t)gr*D))[k4]
                            : make_float4(0.f,0.f,0.f,0.f);
    if (FUSE_BN){
      float4 sc = ((const float4*)sBsc)[k4];
      float4 sh = ((const float4*)sBsh)[k4];
      v.x = fmaf(v.x, sc.x, sh.x); v.y = fmaf(v.y, sc.y, sh.y);
      v.z = fmaf(v.z, sc.z, sh.z); v.w = fmaf(v.w, sc.w, sh.w);
      v.x = v.x > 0.f ? v.x : expm1f(v.x);
      v.y = v.y > 0.f ? v.y : expm1f(v.y);
      v.z = v.z > 0.f ? v.z : expm1f(v.z);
      v.w = v.w > 0.f ? v.w : expm1f(v.w);
    }
    *(uint2*)&Xs[r*136 + k4*4] = make_uint2(pack2(v.x, v.y), pack2(v.z, v.w));
  }
  // ---- stage W transposed (f32 [k][c] -> bf16 [c][k]) ----
  {
    int c = tid & 127, kp = tid >> 7;      // kp 0..3
    #pragma unroll
    for (int t = 0; t < 16; t++){
      int kk = kp + t*4;                   // k-pair index 0..63
      float w0 = W[(size_t)(2*kk)*D + c];
      float w1 = W[(size_t)(2*kk+1)*D + c];
      *(u32*)&WT[c*136 + 2*kk] = pack2(w0, w1);
    }
  }
  __syncthreads();
  int w = tid >> 6, l = tid & 63;
  int l15 = l & 15, lq = l >> 4;
  int cw = w*16;
  bf16x8 bfr[4];
  #pragma unroll
  for (int ks = 0; ks < 4; ks++)
    bfr[ks] = *(const bf16x8*)&WT[(cw + l15)*136 + ks*32 + lq*8];
  f32x4 acc[8];
  #pragma unroll
  for (int m = 0; m < 8; m++) acc[m] = (f32x4){0.f,0.f,0.f,0.f};
  #pragma unroll
  for (int m = 0; m < 8; m++){
    #pragma unroll
    for (int ks = 0; ks < 4; ks++){
      bf16x8 af = *(const bf16x8*)&Xs[(m*16 + l15)*136 + ks*32 + lq*8];
      acc[m] = __builtin_amdgcn_mfma_f32_16x16x32_bf16(af, bfr[ks], acc[m], 0, 0, 0);
    }
  }
  __syncthreads();                          // Xs reads done; alias sDot onto Xs
  float* sDotS = (float*)Xs;                // [8 waves][128 rows]
  float* sDotD = sDotS + 1024;
  // ---- fused attention dots ----
  {
    float as_c = att_s[cw + l15];
    float ad_c = att_d[cw + l15];
    #pragma unroll
    for (int m = 0; m < 8; m++){
      #pragma unroll
      for (int i = 0; i < 4; i++){
        float ps = acc[m][i] * as_c;
        float pd = acc[m][i] * ad_c;
        #pragma unroll
        for (int msk = 1; msk <= 8; msk <<= 1){
          ps += __shfl_xor(ps, msk);
          pd += __shfl_xor(pd, msk);
        }
        if (l15 == 0){
          int r = m*16 + lq*4 + i;
          sDotS[w*128 + r] = ps;
          sDotD[w*128 + r] = pd;
        }
      }
    }
  }
  // ---- C store (row-major): pack bf16 pairs via shfl ----
  #pragma unroll
  for (int m = 0; m < 8; m++){
    #pragma unroll
    for (int i = 0; i < 4; i++){
      float v = acc[m][i];
      float nb = __shfl_xor(v, 1);
      if (!(l & 1)){
        int gr = row0 + m*16 + lq*4 + i;
        if (gr < nrows)
          *(u32*)&Ybf[(size_t)gr*D + cw + l15] = pack2(v, nb);
      }
    }
  }
  __syncthreads();
  {
    int r = tid >> 2, h = tid & 3;          // 512 threads: 128 rows x 4 heads
    int gr = row0 + r;
    if (gr < nrows){
      asrc[gr*4 + h] = sDotS[(2*h)*128 + r] + sDotS[(2*h+1)*128 + r];
      adst[gr*4 + h] = sDotD[(2*h)*128 + r] + sDotD[(2*h+1)*128 + r];
    }
  }
}

// ---------------- GAT edge softmax + aggregate: single pass, no max shift ------
__global__ __launch_bounds__(256) void k_edge(
                       const u16* __restrict__ hb, const float* __restrict__ asrc,
                       const float* __restrict__ adst, const int* __restrict__ offs,
                       const int* __restrict__ srcs, const float* __restrict__ bias,
                       float* __restrict__ out){
  __shared__ uint2 sPk[4][4][17];   // {byte offset src*256, alpha bits}
  int w = threadIdx.x >> 6;
  int lane = threadIdx.x & 63;
  int n = blockIdx.x*4 + w;
  int off0 = offs[n];
  int deg  = offs[n+1] - off0;
  int hd = lane >> 4, j16 = lane & 15;
  float adh = adst[n*4 + hd];
  int half = lane >> 5, q = lane & 31;
  int hg = q >> 3;
  int qb = q*8;
  float denp = 0.f;
  float acc0=0.f, acc1=0.f, acc2=0.f, acc3=0.f;
  const char* hbase = (const char*)hb;
  const int* sp = srcs + off0;
  // preload chunk 0 alpha inputs
  int sj = (j16 < deg) ? sp[j16] : 0;
  float av = asrc[sj*4 + hd];
  for (int base = 0; base < deg; base += 16){
    int lim = deg - base; if (lim > 16) lim = 16;
    // ---- prefetch next chunk's srcs ----
    int nbase = base + 16;
    bool hasn = (nbase < deg);
    int sjn = 0;
    if (hasn){
      int idx = nbase + j16;
      sjn = (idx < deg) ? sp[idx] : 0;
    }
    // ---- alpha for current chunk ----
    float al;
    if (j16 < lim){
      float e = av + adh;
      e = e > 0.f ? e : 0.2f*e;
      al = __expf(e);
    } else al = 0.f;
    denp += al;
    sPk[w][hd][j16] = make_uint2((u32)sj << 8, __float_as_uint(al));
    // ---- prefetch next chunk's asrc (depends on sjn) ----
    float avn = hasn ? asrc[sjn*4 + hd] : 0.f;
    // ---- gather + accumulate ----
    if (lim == 16){
      uint2 p0 = sPk[w][hg][half],      p1 = sPk[w][hg][2+half];
      uint2 p2 = sPk[w][hg][4+half],    p3 = sPk[w][hg][6+half];
      uint2 p4 = sPk[w][hg][8+half],    p5 = sPk[w][hg][10+half];
      uint2 p6 = sPk[w][hg][12+half],   p7 = sPk[w][hg][14+half];
      uint2 v0 = *(const uint2*)(hbase + p0.x + qb);
      uint2 v1 = *(const uint2*)(hbase + p1.x + qb);
      uint2 v2 = *(const uint2*)(hbase + p2.x + qb);
      uint2 v3 = *(const uint2*)(hbase + p3.x + qb);
      uint2 v4 = *(const uint2*)(hbase + p4.x + qb);
      uint2 v5 = *(const uint2*)(hbase + p5.x + qb);
      uint2 v6 = *(const uint2*)(hbase + p6.x + qb);
      uint2 v7 = *(const uint2*)(hbase + p7.x + qb);
      float a0 = __uint_as_float(p0.y), a1 = __uint_as_float(p1.y);
      float a2 = __uint_as_float(p2.y), a3 = __uint_as_float(p3.y);
      float a4 = __uint_as_float(p4.y), a5 = __uint_as_float(p5.y);
      float a6 = __uint_as_float(p6.y), a7 = __uint_as_float(p7.y);
      acc0 = fmaf(a0, lo16f(v0.x), acc0); acc1 = fmaf(a0, hi16f(v0.x), acc1);
      acc2 = fmaf(a0, lo16f(v0.y), acc2); acc3 = fmaf(a0, hi16f(v0.y), acc3);
      acc0 = fmaf(a1, lo16f(v1.x), acc0); acc1 = fmaf(a1, hi16f(v1.x), acc1);
      acc2 = fmaf(a1, lo16f(v1.y), acc2); acc3 = fmaf(a1, hi16f(v1.y), acc3);
      acc0 = fmaf(a2, lo16f(v2.x), acc0); acc1 = fmaf(a2, hi16f(v2.x), acc1);
      acc2 = fmaf(a2, lo16f(v2.y), acc2); acc3 = fmaf(a2, hi16f(v2.y), acc3);
      acc0 = fmaf(a3, lo16f(v3.x), acc0); acc1 = fmaf(a3, hi16f(v3.x), acc1);
      acc2 = fmaf(a3, lo16f(v3.y), acc2); acc3 = fmaf(a3, hi16f(v3.y), acc3);
      acc0 = fmaf(a4, lo16f(v4.x), acc0); acc1 = fmaf(a4, hi16f(v4.x), acc1);
      acc2 = fmaf(a4, lo16f(v4.y), acc2); acc3 = fmaf(a4, hi16f(v4.y), acc3);
      acc0 = fmaf(a5, lo16f(v5.x), acc0); acc1 = fmaf(a5, hi16f(v5.x), acc1);
      acc2 = fmaf(a5, lo16f(v5.y), acc2); acc3 = fmaf(a5, hi16f(v5.y), acc3);
      acc0 = fmaf(a6, lo16f(v6.x), acc0); acc1 = fmaf(a6, hi16f(v6.x), acc1);
      acc2 = fmaf(a6, lo16f(v6.y), acc2); acc3 = fmaf(a6, hi16f(v6.y), acc3);
      acc0 = fmaf(a7, lo16f(v7.x), acc0); acc1 = fmaf(a7, hi16f(v7.x), acc1);
      acc2 = fmaf(a7, lo16f(v7.y), acc2); acc3 = fmaf(a7, hi16f(v7.y), acc3);
    } else {
      for (int j = 0; j < lim; j += 8){
        uint2 pA = sPk[w][hg][j+half],   pB = sPk[w][hg][j+2+half];
        uint2 pC = sPk[w][hg][j+4+half], pD = sPk[w][hg][j+6+half];
        uint2 vA = *(const uint2*)(hbase + pA.x + qb);
        uint2 vB = *(const uint2*)(hbase + pB.x + qb);
        uint2 vC = *(const uint2*)(hbase + pC.x + qb);
        uint2 vD = *(const uint2*)(hbase + pD.x + qb);
        float aA = __uint_as_float(pA.y), aB = __uint_as_float(pB.y);
        float aC = __uint_as_float(pC.y), aD = __uint_as_float(pD.y);
        acc0 = fmaf(aA, lo16f(vA.x), acc0); acc1 = fmaf(aA, hi16f(vA.x), acc1);
        acc2 = fmaf(aA, lo16f(vA.y), acc2); acc3 = fmaf(aA, hi16f(vA.y), acc3);
        acc0 = fmaf(aB, lo16f(vB.x), acc0); acc1 = fmaf(aB, hi16f(vB.x), acc1);
        acc2 = fmaf(aB, lo16f(vB.y), acc2); acc3 = fmaf(aB, hi16f(vB.y), acc3);
        acc0 = fmaf(aC, lo16f(vC.x), acc0); acc1 = fmaf(aC, hi16f(vC.x), acc1);
        acc2 = fmaf(aC, lo16f(vC.y), acc2); acc3 = fmaf(aC, hi16f(vC.y), acc3);
        acc0 = fmaf(aD, lo16f(vD.x), acc0); acc1 = fmaf(aD, hi16f(vD.x), acc1);
        acc2 = fmaf(aD, lo16f(vD.y), acc2); acc3 = fmaf(aD, hi16f(vD.y), acc3);
      }
    }
    sj = sjn; av = avn;
  }
  denp += __shfl_xor(denp, 1);
  denp += __shfl_xor(denp, 2);
  denp += __shfl_xor(denp, 4);
  denp += __shfl_xor(denp, 8);
  acc0 += __shfl_xor(acc0, 32);
  acc1 += __shfl_xor(acc1, 32);
  acc2 += __shfl_xor(acc2, 32);
  acc3 += __shfl_xor(acc3, 32);
  float inv = 1.f / __shfl(denp, hg*16);
  if (half == 0){
    int cb = q*4;
    float4 o;
    o.x = acc0*inv + bias[cb];
    o.y = acc1*inv + bias[cb+1];
    o.z = acc2*inv + bias[cb+2];
    o.w = acc3*inv + bias[cb+3];
    ((float4*)(out + (size_t)n*D))[q] = o;
  }
}

// ---------------- BatchNorm stats (f32 input) ----------------
__global__ __launch_bounds__(256) void k_bnstat(const float* __restrict__ B,
                                                float* __restrict__ bsum, float* __restrict__ bsq){
  __shared__ float sS[256], sQ[256];
  int tid = threadIdx.x;
  int c = tid & 127;
  int rr = tid >> 7;
  int r0 = blockIdx.x * 64;
  int r1 = r0 + 64; if (r1 > NN) r1 = NN;
  float s = 0.f, qv = 0.f;
  for (int r = r0 + rr; r < r1; r += 2){
    float v = B[(size_t)r*D + c];
    s += v; qv += v*v;
  }
  sS[tid] = s; sQ[tid] = qv;
  __syncthreads();
  if (tid < 128){
    atomicAdd(&bsum[c], sS[tid] + sS[tid+128]);
    atomicAdd(&bsq[c],  sQ[tid] + sQ[tid+128]);
  }
}

// ---------------- global mean pool (batch sorted) ----------------
#define POOL_ROWS 50
__global__ void k_poolA(const float* __restrict__ h2, const int* __restrict__ batch,
                        float* __restrict__ pooled){
  int c = threadIdx.x & 127;
  int half = threadIdx.x >> 7;
  int r0 = blockIdx.x * POOL_ROWS;
  int r1 = r0 + POOL_ROWS; if (r1 > NN) r1 = NN;
  float s = 0.f; int g = -1;
  for (int r = r0 + half; r < r1; r += 2){
    int bg = batch[r];
    if (bg != g){
      if (g >= 0) atomicAdd(&pooled[g*D + c], s);
      g = bg; s = 0.f;
    }
    s += h2[(size_t)r*D + c];
  }
  if (g >= 0) atomicAdd(&pooled[g*D + c], s);
}

__global__ void k_poolB(const float* __restrict__ pooled, const int* __restrict__ batch,
                        float* __restrict__ out){
  int g = blockIdx.x;
  int c = threadIdx.x;   // 128
  int lo = 0, hi = NN;
  while (lo < hi){ int mid = (lo+hi) >> 1; if (batch[mid] < g) lo = mid+1; else hi = mid; }
  int a = lo, b = NN;
  while (a < b){ int mid = (a+b) >> 1; if (batch[mid] < g+1) a = mid+1; else b = mid; }
  int cntg = a - lo;
  out[g*D + c] = pooled[g*D + c] / (float)(cntg > 1 ? cntg : 1);
}

extern "C" void kernel_launch(void* const* d_in, const int* in_sizes, int n_in,
                              void* d_out, int out_size, void* d_ws, size_t ws_size,
                              hipStream_t stream){
  (void)in_sizes; (void)n_in; (void)out_size; (void)ws_size;
  const float* x   = (const float*)d_in[0];
  const int* ei    = (const int*)d_in[1];
  const int* batch = (const int*)d_in[2];
  const float* W1  = (const float*)d_in[3];
  const float* as1 = (const float*)d_in[4];
  const float* ad1 = (const float*)d_in[5];
  const float* b1  = (const float*)d_in[6];
  const float* g1  = (const float*)d_in[7];
  const float* be1 = (const float*)d_in[8];
  const float* W2  = (const float*)d_in[9];
  const float* as2 = (const float*)d_in[10];
  const float* ad2 = (const float*)d_in[11];
  const float* b2  = (const float*)d_in[12];
  float* outp = (float*)d_out;

  float* B    = (float*)d_ws;            // 6.4M f32
  float* asr  = B + 6400000;             // 200K
  float* ads  = asr + 200000;            // 200K
  // ---- contiguous zero-block (zeroed by k_gemm<0> prologue) ----
  float* bsum = ads + 200000;            // 128
  float* bsq  = bsum + 128;              // 128
  float* pooled = bsq + 128;             // 8192
  int* gCur   = (int*)(pooled + NG*D);   // 256
  // ---- end zero-block (8704 words) ----
  int* offs   = gCur + 256;              // 50001
  int* srcs   = offs + (NN+1);           // 850000
  int* temp   = srcs + ET;               // 196*5120 = 1003520
  u16* hb     = (u16*)(temp + NB*CAP);   // 6.4M bf16 (12.8 MB)
  u32* zbase  = (u32*)bsum;
  const int ZWORDS = 128 + 128 + NG*D + 256;   // 8704

  const int* srcE = ei;
  const int* dstE = ei + NE;

  // layer-1 GEMM (+att dots, + scratch zeroing)
  k_gemm<0><<<391, 512, 0, stream>>>(x, W1, hb, as1, ad1, asr, ads,
                                     nullptr, nullptr, nullptr, nullptr,
                                     zbase, ZWORDS, NN);
  // CSR build: bucket -> place (bucket starts inline)
  k_bucket<<<(NE + CHUNK - 1)/CHUNK, 256, 0, stream>>>(srcE, dstE, gCur, temp);
  k_place<<<NB, 256, 0, stream>>>(temp, gCur, offs, srcs);
  k_edge<<<NN/4, 256, 0, stream>>>(hb, asr, ads, offs, srcs, b1, B);
  k_bnstat<<<782, 256, 0, stream>>>(B, bsum, bsq);
  // layer-2 GEMM: fused BN-finalize + BN+ELU on input (+att dots)
  k_gemm<1><<<391, 512, 0, stream>>>(B, W2, hb, as2, ad2, asr, ads,
                                     bsum, bsq, g1, be1, nullptr, 0, NN);
  k_edge<<<NN/4, 256, 0, stream>>>(hb, asr, ads, offs, srcs, b2, outp);
  // pool
  k_poolA<<<(NN + POOL_ROWS - 1)/POOL_ROWS, 256, 0, stream>>>(outp, batch, pooled);
  k_poolB<<<NG, 128, 0, stream>>>(pooled, batch, outp + 6400000);
}